// Round 4
// baseline (521.002 us; speedup 1.0000x reference)
//
#include <hip/hip_runtime.h>

// MinkowskiUnion: out[map_out[i]] += feat[map_in[i]] for two input tensors.
// Preferred path: K=4 sentinel slot table + overflow list.
//   hdr[0]      = overflow counter (zeroed)
//   cnt[r]      = atomic counter per output row, init -1 (memset 0xFF)
//   slots[4r+p] = packed (tensor_bit<<30 | in_row), init -1; p = atomicAdd(cnt)+1
//   ovf list    = rare entries with p>=4, applied via f32 atomics after gather
//   gather      = each out row sums slots != -1, single NT write, no f32 atomics
// Fill is XCD-partitioned: 8 groups (blockIdx&7 -> XCD via round-robin dispatch),
// each scans all maps but only handles rows in its 1/8 range, so slot stores
// stay inside the local 4 MiB L2 (3 MB working set) instead of thrashing 24 MB.
// Fallbacks: CSR counting-sort, then plain atomic scatter.

#define ROW_C 64
#define TBIT (1 << 30)
#define OVF_CAP (1 << 20)
#define NXCD 8
#define FILL_BPG 1024
#define SCAN_T 256
#define SCAN_PER 16
#define SCAN_CHUNK (SCAN_T * SCAN_PER)

typedef float f32x4 __attribute__((ext_vector_type(4)));

// ---------- slot path ----------
__global__ __launch_bounds__(256) void k_fill_part(
        const int* __restrict__ m_in, const int* __restrict__ m_out,
        int n, int tbit, int M,
        int* __restrict__ cnt, int* __restrict__ slots,
        int* __restrict__ ovf, int* __restrict__ ovf_n) {
    int g   = blockIdx.x & (NXCD - 1);       // partition group ~ XCD
    int b   = blockIdx.x >> 3;
    int bpg = gridDim.x >> 3;
    int lo = (int)(((long long)g * M) / NXCD);
    int hi = (int)(((long long)(g + 1) * M) / NXCD);
    int nchunk = (n + 3) >> 2;
    for (int c = b * blockDim.x + threadIdx.x; c < nchunk; c += bpg * blockDim.x) {
        int i0 = c << 2;
        int rr[4], vv[4];
        if (i0 + 3 < n) {
            int4 ro = *reinterpret_cast<const int4*>(m_out + i0);
            int4 ri = *reinterpret_cast<const int4*>(m_in + i0);
            rr[0] = ro.x; rr[1] = ro.y; rr[2] = ro.z; rr[3] = ro.w;
            vv[0] = ri.x; vv[1] = ri.y; vv[2] = ri.z; vv[3] = ri.w;
        } else {
            for (int k = 0; k < 4; k++) {
                int i = i0 + k;
                rr[k] = (i < n) ? m_out[i] : -1;   // -1 fails range check
                vv[k] = (i < n) ? m_in[i] : 0;
            }
        }
#pragma unroll
        for (int k = 0; k < 4; k++) {
            int r = rr[k];
            if (r >= lo && r < hi) {
                int pos = atomicAdd(&cnt[r], 1) + 1;   // cnt starts at -1
                int v = vv[k] | tbit;
                if (pos < 4) {
                    slots[(r << 2) + pos] = v;
                } else {
                    int p = atomicAdd(ovf_n, 1);
                    if (p < OVF_CAP) { ovf[2 * p] = r; ovf[2 * p + 1] = v; }
                }
            }
        }
    }
}

__global__ __launch_bounds__(256) void k_gather_slots(
        const float* __restrict__ feat1, const float* __restrict__ feat2,
        const int* __restrict__ slots, float* __restrict__ out, int M) {
    int gid = blockIdx.x * blockDim.x + threadIdx.x;
    int row = gid >> 4;                 // 16 threads per output row
    if (row >= M) return;
    int sub = (gid & 15) << 2;

    const int4 s = *reinterpret_cast<const int4*>(slots + (row << 2));  // broadcast
    int e[4] = { s.x, s.y, s.z, s.w };

    f32x4 acc = {0.f, 0.f, 0.f, 0.f};
#pragma unroll
    for (int k = 0; k < 4; k++) {
        int v = e[k];
        if (v != -1) {
            const float* f = (v & TBIT) ? feat2 : feat1;
            int in_r = v & (TBIT - 1);
            f32x4 x = *reinterpret_cast<const f32x4*>(f + (size_t)in_r * ROW_C + sub);
            acc += x;
        }
    }
    __builtin_nontemporal_store(acc,
        reinterpret_cast<f32x4*>(out + (size_t)row * ROW_C + sub));
}

__global__ void k_overflow(const int* __restrict__ ovf_n, const int* __restrict__ ovf,
                           const float* __restrict__ feat1, const float* __restrict__ feat2,
                           float* __restrict__ out) {
    int total = *ovf_n;
    if (total > OVF_CAP) total = OVF_CAP;
    int stride = gridDim.x * blockDim.x;
    for (int idx = blockIdx.x * blockDim.x + threadIdx.x; idx < total * 16; idx += stride) {
        int e = idx >> 4;
        int sub = (idx & 15) << 2;
        int r = ovf[2 * e];
        int v = ovf[2 * e + 1];
        const float* f = (v & TBIT) ? feat2 : feat1;
        int in_r = v & (TBIT - 1);
        float4 x = *reinterpret_cast<const float4*>(f + (size_t)in_r * ROW_C + sub);
        float* o = out + (size_t)r * ROW_C + sub;
        unsafeAtomicAdd(o + 0, x.x);
        unsafeAtomicAdd(o + 1, x.y);
        unsafeAtomicAdd(o + 2, x.z);
        unsafeAtomicAdd(o + 3, x.w);
    }
}

// ---------- CSR fallback ----------
__global__ void k_hist(const int* __restrict__ map_out, int n, int* __restrict__ counts) {
    int i = blockIdx.x * blockDim.x + threadIdx.x;
    if (i < n) atomicAdd(&counts[map_out[i]], 1);
}

__global__ void k_partial(const int* __restrict__ counts, int M, int* __restrict__ bsum) {
    __shared__ int lds[SCAN_T];
    int base = blockIdx.x * SCAN_CHUNK + threadIdx.x * SCAN_PER;
    int s = 0;
#pragma unroll
    for (int k = 0; k < SCAN_PER; k++) { int i = base + k; if (i < M) s += counts[i]; }
    lds[threadIdx.x] = s; __syncthreads();
    for (int off = SCAN_T / 2; off > 0; off >>= 1) {
        if (threadIdx.x < off) lds[threadIdx.x] += lds[threadIdx.x + off];
        __syncthreads();
    }
    if (threadIdx.x == 0) bsum[blockIdx.x] = lds[0];
}

__global__ void k_scan_bsum(int* __restrict__ bsum, int nblk) {
    __shared__ int lds[512];
    int t = threadIdx.x;
    lds[t] = (t < nblk) ? bsum[t] : 0;
    __syncthreads();
    for (int off = 1; off < 512; off <<= 1) {
        int v = (t >= off) ? lds[t - off] : 0;
        __syncthreads();
        lds[t] += v;
        __syncthreads();
    }
    if (t < nblk) bsum[t] = (t == 0) ? 0 : lds[t - 1];
}

__global__ void k_offsets(const int* __restrict__ counts, int M,
                          const int* __restrict__ bsum, int* __restrict__ cursor) {
    __shared__ int lds[SCAN_T];
    int base = blockIdx.x * SCAN_CHUNK + threadIdx.x * SCAN_PER;
    int c[SCAN_PER]; int s = 0;
#pragma unroll
    for (int k = 0; k < SCAN_PER; k++) { int i = base + k; c[k] = (i < M) ? counts[i] : 0; s += c[k]; }
    lds[threadIdx.x] = s; __syncthreads();
    for (int off = 1; off < SCAN_T; off <<= 1) {
        int v = (threadIdx.x >= off) ? lds[threadIdx.x - off] : 0;
        __syncthreads();
        lds[threadIdx.x] += v;
        __syncthreads();
    }
    int prefix = bsum[blockIdx.x] + ((threadIdx.x == 0) ? 0 : lds[threadIdx.x - 1]);
#pragma unroll
    for (int k = 0; k < SCAN_PER; k++) { int i = base + k; if (i < M) cursor[i] = prefix; prefix += c[k]; }
}

__global__ void k_fill(const int* __restrict__ map_in, const int* __restrict__ map_out,
                       int n, int tbit, int* __restrict__ cursor, int* __restrict__ csr) {
    int i = blockIdx.x * blockDim.x + threadIdx.x;
    if (i >= n) return;
    int r = map_out[i];
    int pos = atomicAdd(&cursor[r], 1);
    csr[pos] = map_in[i] | tbit;
}

__global__ void k_gather(const float* __restrict__ feat1, const float* __restrict__ feat2,
                         const int* __restrict__ counts, const int* __restrict__ cursor,
                         const int* __restrict__ csr, float* __restrict__ out, int M) {
    int gid = blockIdx.x * blockDim.x + threadIdx.x;
    int row = gid >> 4;
    if (row >= M) return;
    int sub = (gid & 15) << 2;

    int cnt = counts[row];
    int end = cursor[row];
    int start = end - cnt;

    float4 acc = {0.f, 0.f, 0.f, 0.f};
    for (int k = 0; k < cnt; k++) {
        int e = csr[start + k];
        const float* f = (e & TBIT) ? feat2 : feat1;
        int in_r = e & (TBIT - 1);
        float4 v = *reinterpret_cast<const float4*>(f + (size_t)in_r * ROW_C + sub);
        acc.x += v.x; acc.y += v.y; acc.z += v.z; acc.w += v.w;
    }
    *reinterpret_cast<float4*>(out + (size_t)row * ROW_C + sub) = acc;
}

// ---------- last-resort atomic scatter ----------
__global__ void scatter_add_rows(const float* __restrict__ feat,
                                 const int* __restrict__ map_in,
                                 const int* __restrict__ map_out,
                                 float* __restrict__ out,
                                 int n_rows) {
    int gid = blockIdx.x * blockDim.x + threadIdx.x;
    int row = gid >> 4;
    if (row >= n_rows) return;
    int sub = (gid & 15) << 2;
    int in_r  = map_in[row];
    int out_r = map_out[row];
    const float4 v = *reinterpret_cast<const float4*>(feat + (size_t)in_r * ROW_C + sub);
    float* o = out + (size_t)out_r * ROW_C + sub;
    unsafeAtomicAdd(o + 0, v.x);
    unsafeAtomicAdd(o + 1, v.y);
    unsafeAtomicAdd(o + 2, v.z);
    unsafeAtomicAdd(o + 3, v.w);
}

extern "C" void kernel_launch(void* const* d_in, const int* in_sizes, int n_in,
                              void* d_out, int out_size, void* d_ws, size_t ws_size,
                              hipStream_t stream) {
    const float* feat1    = (const float*)d_in[0];
    const float* feat2    = (const float*)d_in[1];
    const int*   map1_in  = (const int*)d_in[2];
    const int*   map1_out = (const int*)d_in[3];
    const int*   map2_in  = (const int*)d_in[4];
    const int*   map2_out = (const int*)d_in[5];
    float* out = (float*)d_out;

    const int n1 = in_sizes[2];
    const int n2 = in_sizes[4];
    const int M  = out_size / ROW_C;
    const int ntot = n1 + n2;
    const int block = 256;

    // ---- slot path ----
    // layout: hdr(64B: ovf_n at [0]) | cnt[M] | slots[4M] | ovf[2*OVF_CAP]
    const size_t need_slots = 64 + (5 * (size_t)M + 2 * (size_t)OVF_CAP) * sizeof(int);
    if (ws_size >= need_slots) {
        int* hdr   = (int*)d_ws;
        int* cnt   = hdr + 16;
        int* slots = cnt + M;
        int* ovf   = slots + 4 * (size_t)M;

        hipMemsetAsync(hdr, 0, 64, stream);
        hipMemsetAsync(cnt, 0xFF, 5 * (size_t)M * sizeof(int), stream);  // cnt=-1, slots=-1

        const int gridf = NXCD * FILL_BPG;
        k_fill_part<<<gridf, block, 0, stream>>>(map1_in, map1_out, n1, 0,    M, cnt, slots, ovf, hdr);
        k_fill_part<<<gridf, block, 0, stream>>>(map2_in, map2_out, n2, TBIT, M, cnt, slots, ovf, hdr);

        int gridg = (int)(((long long)M * 16 + block - 1) / block);
        k_gather_slots<<<gridg, block, 0, stream>>>(feat1, feat2, slots, out, M);

        k_overflow<<<512, block, 0, stream>>>(hdr, ovf, feat1, feat2, out);
        return;
    }

    // ---- CSR fallback ----
    const int nblk = (M + SCAN_CHUNK - 1) / SCAN_CHUNK;
    const size_t need_csr = (size_t)(2 * (size_t)M + (size_t)ntot + (size_t)nblk) * sizeof(int);
    if (ws_size >= need_csr && nblk <= 512) {
        int* counts = (int*)d_ws;
        int* cursor = counts + M;
        int* csr    = cursor + M;
        int* bsum   = csr + ntot;

        hipMemsetAsync(counts, 0, (size_t)M * sizeof(int), stream);
        k_hist<<<(n1 + block - 1) / block, block, 0, stream>>>(map1_out, n1, counts);
        k_hist<<<(n2 + block - 1) / block, block, 0, stream>>>(map2_out, n2, counts);
        k_partial<<<nblk, SCAN_T, 0, stream>>>(counts, M, bsum);
        k_scan_bsum<<<1, 512, 0, stream>>>(bsum, nblk);
        k_offsets<<<nblk, SCAN_T, 0, stream>>>(counts, M, bsum, cursor);
        k_fill<<<(n1 + block - 1) / block, block, 0, stream>>>(map1_in, map1_out, n1, 0, cursor, csr);
        k_fill<<<(n2 + block - 1) / block, block, 0, stream>>>(map2_in, map2_out, n2, TBIT, cursor, csr);
        int gridg = (int)(((long long)M * 16 + block - 1) / block);
        k_gather<<<gridg, block, 0, stream>>>(feat1, feat2, counts, cursor, csr, out, M);
        return;
    }

    // ---- atomic scatter ----
    hipMemsetAsync(out, 0, (size_t)out_size * sizeof(float), stream);
    int grid1 = (int)(((long long)n1 * 16 + block - 1) / block);
    int grid2 = (int)(((long long)n2 * 16 + block - 1) / block);
    scatter_add_rows<<<grid1, block, 0, stream>>>(feat1, map1_in, map1_out, out, n1);
    scatter_add_rows<<<grid2, block, 0, stream>>>(feat2, map2_in, map2_out, out, n2);
}

// Round 5
// 423.839 us; speedup vs baseline: 1.2292x; 1.2292x over previous
//
#include <hip/hip_runtime.h>

// MinkowskiUnion: out[map_out[i]] += feat[map_in[i]] for two input tensors.
// Slot path v3: merged 32B row records so the per-entry atomic (cnt) and the
// dependent slot store land in the SAME 64B cacheline (halves random-line
// touches vs separate cnt[]/slots[] arrays — fill is random-miss-concurrency
// bound, not bandwidth bound).
//   rec[r] = { s0, s1, s2, s3, cnt, pad, pad, pad }  (32B, init 0xFF)
//   pos = atomicAdd(&rec[r].cnt, 1) + 1   (cnt starts at -1)
//   p<4 -> rec[r].s[p] = v ;  else -> overflow list (f32 atomics after gather)
//   gather: 16 lanes/row read slot quad, sum feat rows, one NT store. No cnt read.
// Fallbacks: CSR counting-sort, then plain atomic scatter.

#define ROW_C 64
#define TBIT (1 << 30)
#define OVF_CAP (1 << 20)
#define SCAN_T 256
#define SCAN_PER 16
#define SCAN_CHUNK (SCAN_T * SCAN_PER)

typedef float f32x4 __attribute__((ext_vector_type(4)));

// ---------- record slot path ----------
__global__ __launch_bounds__(256) void k_fill_rec(
        const int* __restrict__ m1i, const int* __restrict__ m1o,
        const int* __restrict__ m2i, const int* __restrict__ m2o,
        int n1, int n2,
        int* __restrict__ rec,          // 8 ints per row: s0..s3, cnt, pad*3
        int* __restrict__ ovf, int* __restrict__ ovf_n) {
    int i = blockIdx.x * blockDim.x + threadIdx.x;
    int r, v;
    if (i < n1) { r = m1o[i]; v = m1i[i]; }
    else {
        int j = i - n1;
        if (j >= n2) return;
        r = m2o[j]; v = m2i[j] | TBIT;
    }
    int* base = rec + ((size_t)r << 3);
    int pos = atomicAdd(base + 4, 1) + 1;   // cnt init -1; same 64B line as s[]
    if (pos < 4) {
        base[pos] = v;
    } else {
        int p = atomicAdd(ovf_n, 1);
        if (p < OVF_CAP) { ovf[2 * p] = r; ovf[2 * p + 1] = v; }
    }
}

__global__ __launch_bounds__(256) void k_gather_rec(
        const float* __restrict__ feat1, const float* __restrict__ feat2,
        const int* __restrict__ rec, float* __restrict__ out, int M) {
    int gid = blockIdx.x * blockDim.x + threadIdx.x;
    int row = gid >> 4;                 // 16 threads per output row
    if (row >= M) return;
    int sub = (gid & 15) << 2;

    const int4 s = *reinterpret_cast<const int4*>(rec + ((size_t)row << 3));  // broadcast
    int e[4] = { s.x, s.y, s.z, s.w };

    f32x4 acc = {0.f, 0.f, 0.f, 0.f};
#pragma unroll
    for (int k = 0; k < 4; k++) {
        int v = e[k];
        if (v != -1) {
            const float* f = (v & TBIT) ? feat2 : feat1;
            int in_r = v & (TBIT - 1);
            f32x4 x = *reinterpret_cast<const f32x4*>(f + (size_t)in_r * ROW_C + sub);
            acc += x;
        }
    }
    __builtin_nontemporal_store(acc,
        reinterpret_cast<f32x4*>(out + (size_t)row * ROW_C + sub));
}

__global__ void k_overflow(const int* __restrict__ ovf_n, const int* __restrict__ ovf,
                           const float* __restrict__ feat1, const float* __restrict__ feat2,
                           float* __restrict__ out) {
    int total = *ovf_n;
    if (total > OVF_CAP) total = OVF_CAP;
    int stride = gridDim.x * blockDim.x;
    for (int idx = blockIdx.x * blockDim.x + threadIdx.x; idx < total * 16; idx += stride) {
        int e = idx >> 4;
        int sub = (idx & 15) << 2;
        int r = ovf[2 * e];
        int v = ovf[2 * e + 1];
        const float* f = (v & TBIT) ? feat2 : feat1;
        int in_r = v & (TBIT - 1);
        float4 x = *reinterpret_cast<const float4*>(f + (size_t)in_r * ROW_C + sub);
        float* o = out + (size_t)r * ROW_C + sub;
        unsafeAtomicAdd(o + 0, x.x);
        unsafeAtomicAdd(o + 1, x.y);
        unsafeAtomicAdd(o + 2, x.z);
        unsafeAtomicAdd(o + 3, x.w);
    }
}

// ---------- CSR fallback ----------
__global__ void k_hist(const int* __restrict__ map_out, int n, int* __restrict__ counts) {
    int i = blockIdx.x * blockDim.x + threadIdx.x;
    if (i < n) atomicAdd(&counts[map_out[i]], 1);
}

__global__ void k_partial(const int* __restrict__ counts, int M, int* __restrict__ bsum) {
    __shared__ int lds[SCAN_T];
    int base = blockIdx.x * SCAN_CHUNK + threadIdx.x * SCAN_PER;
    int s = 0;
#pragma unroll
    for (int k = 0; k < SCAN_PER; k++) { int i = base + k; if (i < M) s += counts[i]; }
    lds[threadIdx.x] = s; __syncthreads();
    for (int off = SCAN_T / 2; off > 0; off >>= 1) {
        if (threadIdx.x < off) lds[threadIdx.x] += lds[threadIdx.x + off];
        __syncthreads();
    }
    if (threadIdx.x == 0) bsum[blockIdx.x] = lds[0];
}

__global__ void k_scan_bsum(int* __restrict__ bsum, int nblk) {
    __shared__ int lds[512];
    int t = threadIdx.x;
    lds[t] = (t < nblk) ? bsum[t] : 0;
    __syncthreads();
    for (int off = 1; off < 512; off <<= 1) {
        int v = (t >= off) ? lds[t - off] : 0;
        __syncthreads();
        lds[t] += v;
        __syncthreads();
    }
    if (t < nblk) bsum[t] = (t == 0) ? 0 : lds[t - 1];
}

__global__ void k_offsets(const int* __restrict__ counts, int M,
                          const int* __restrict__ bsum, int* __restrict__ cursor) {
    __shared__ int lds[SCAN_T];
    int base = blockIdx.x * SCAN_CHUNK + threadIdx.x * SCAN_PER;
    int c[SCAN_PER]; int s = 0;
#pragma unroll
    for (int k = 0; k < SCAN_PER; k++) { int i = base + k; c[k] = (i < M) ? counts[i] : 0; s += c[k]; }
    lds[threadIdx.x] = s; __syncthreads();
    for (int off = 1; off < SCAN_T; off <<= 1) {
        int v = (threadIdx.x >= off) ? lds[threadIdx.x - off] : 0;
        __syncthreads();
        lds[threadIdx.x] += v;
        __syncthreads();
    }
    int prefix = bsum[blockIdx.x] + ((threadIdx.x == 0) ? 0 : lds[threadIdx.x - 1]);
#pragma unroll
    for (int k = 0; k < SCAN_PER; k++) { int i = base + k; if (i < M) cursor[i] = prefix; prefix += c[k]; }
}

__global__ void k_fill(const int* __restrict__ map_in, const int* __restrict__ map_out,
                       int n, int tbit, int* __restrict__ cursor, int* __restrict__ csr) {
    int i = blockIdx.x * blockDim.x + threadIdx.x;
    if (i >= n) return;
    int r = map_out[i];
    int pos = atomicAdd(&cursor[r], 1);
    csr[pos] = map_in[i] | tbit;
}

__global__ void k_gather(const float* __restrict__ feat1, const float* __restrict__ feat2,
                         const int* __restrict__ counts, const int* __restrict__ cursor,
                         const int* __restrict__ csr, float* __restrict__ out, int M) {
    int gid = blockIdx.x * blockDim.x + threadIdx.x;
    int row = gid >> 4;
    if (row >= M) return;
    int sub = (gid & 15) << 2;

    int cnt = counts[row];
    int end = cursor[row];
    int start = end - cnt;

    float4 acc = {0.f, 0.f, 0.f, 0.f};
    for (int k = 0; k < cnt; k++) {
        int e = csr[start + k];
        const float* f = (e & TBIT) ? feat2 : feat1;
        int in_r = e & (TBIT - 1);
        float4 v = *reinterpret_cast<const float4*>(f + (size_t)in_r * ROW_C + sub);
        acc.x += v.x; acc.y += v.y; acc.z += v.z; acc.w += v.w;
    }
    *reinterpret_cast<float4*>(out + (size_t)row * ROW_C + sub) = acc;
}

// ---------- last-resort atomic scatter ----------
__global__ void scatter_add_rows(const float* __restrict__ feat,
                                 const int* __restrict__ map_in,
                                 const int* __restrict__ map_out,
                                 float* __restrict__ out,
                                 int n_rows) {
    int gid = blockIdx.x * blockDim.x + threadIdx.x;
    int row = gid >> 4;
    if (row >= n_rows) return;
    int sub = (gid & 15) << 2;
    int in_r  = map_in[row];
    int out_r = map_out[row];
    const float4 v = *reinterpret_cast<const float4*>(feat + (size_t)in_r * ROW_C + sub);
    float* o = out + (size_t)out_r * ROW_C + sub;
    unsafeAtomicAdd(o + 0, v.x);
    unsafeAtomicAdd(o + 1, v.y);
    unsafeAtomicAdd(o + 2, v.z);
    unsafeAtomicAdd(o + 3, v.w);
}

extern "C" void kernel_launch(void* const* d_in, const int* in_sizes, int n_in,
                              void* d_out, int out_size, void* d_ws, size_t ws_size,
                              hipStream_t stream) {
    const float* feat1    = (const float*)d_in[0];
    const float* feat2    = (const float*)d_in[1];
    const int*   map1_in  = (const int*)d_in[2];
    const int*   map1_out = (const int*)d_in[3];
    const int*   map2_in  = (const int*)d_in[4];
    const int*   map2_out = (const int*)d_in[5];
    float* out = (float*)d_out;

    const int n1 = in_sizes[2];
    const int n2 = in_sizes[4];
    const int M  = out_size / ROW_C;
    const int ntot = n1 + n2;
    const int block = 256;

    // ---- record slot path ----
    // layout: hdr(64B: ovf_n at [0]) | rec[M] (32B each) | ovf[2*OVF_CAP]
    const size_t need_rec = 64 + ((size_t)M << 5) + 2 * (size_t)OVF_CAP * sizeof(int);
    if (ws_size >= need_rec) {
        int* hdr = (int*)d_ws;
        int* rec = hdr + 16;                       // 64B-aligned
        int* ovf = rec + ((size_t)M << 3);

        hipMemsetAsync(hdr, 0, 64, stream);
        hipMemsetAsync(rec, 0xFF, (size_t)M << 5, stream);   // s[]=-1, cnt=-1

        int gridf = (ntot + block - 1) / block;
        k_fill_rec<<<gridf, block, 0, stream>>>(map1_in, map1_out, map2_in, map2_out,
                                                n1, n2, rec, ovf, hdr);

        int gridg = (int)(((long long)M * 16 + block - 1) / block);
        k_gather_rec<<<gridg, block, 0, stream>>>(feat1, feat2, rec, out, M);

        k_overflow<<<512, block, 0, stream>>>(hdr, ovf, feat1, feat2, out);
        return;
    }

    // ---- CSR fallback ----
    const int nblk = (M + SCAN_CHUNK - 1) / SCAN_CHUNK;
    const size_t need_csr = (size_t)(2 * (size_t)M + (size_t)ntot + (size_t)nblk) * sizeof(int);
    if (ws_size >= need_csr && nblk <= 512) {
        int* counts = (int*)d_ws;
        int* cursor = counts + M;
        int* csr    = cursor + M;
        int* bsum   = csr + ntot;

        hipMemsetAsync(counts, 0, (size_t)M * sizeof(int), stream);
        k_hist<<<(n1 + block - 1) / block, block, 0, stream>>>(map1_out, n1, counts);
        k_hist<<<(n2 + block - 1) / block, block, 0, stream>>>(map2_out, n2, counts);
        k_partial<<<nblk, SCAN_T, 0, stream>>>(counts, M, bsum);
        k_scan_bsum<<<1, 512, 0, stream>>>(bsum, nblk);
        k_offsets<<<nblk, SCAN_T, 0, stream>>>(counts, M, bsum, cursor);
        k_fill<<<(n1 + block - 1) / block, block, 0, stream>>>(map1_in, map1_out, n1, 0, cursor, csr);
        k_fill<<<(n2 + block - 1) / block, block, 0, stream>>>(map2_in, map2_out, n2, TBIT, cursor, csr);
        int gridg = (int)(((long long)M * 16 + block - 1) / block);
        k_gather<<<gridg, block, 0, stream>>>(feat1, feat2, counts, cursor, csr, out, M);
        return;
    }

    // ---- atomic scatter ----
    hipMemsetAsync(out, 0, (size_t)out_size * sizeof(float), stream);
    int grid1 = (int)(((long long)n1 * 16 + block - 1) / block);
    int grid2 = (int)(((long long)n2 * 16 + block - 1) / block);
    scatter_add_rows<<<grid1, block, 0, stream>>>(feat1, map1_in, map1_out, out, n1);
    scatter_add_rows<<<grid2, block, 0, stream>>>(feat2, map2_in, map2_out, out, n2);
}

// Round 6
// 377.849 us; speedup vs baseline: 1.3789x; 1.1217x over previous
//
#include <hip/hip_runtime.h>

// MinkowskiUnion: out[map_out[i]] += feat[map_in[i]] for two input tensors.
// Linked-list inversion (atomicExch):
//   head[r]    = packed {v:32 | link:32}, init {-1,-1}; 12 MB -> IF-resident
//   fill:        old = atomicExch(&head[r], pack(v, i)); entries[i] = old
//                (random access ONLY in the 12MB head; entries store coalesced)
//   gather:      walk chain, collect up to 4 v's in registers, then issue
//                independent feat row loads; >4 tail accumulates inline.
//                One NT store per output row. No f32 atomics, no overflow list.
// Fallbacks: CSR counting-sort, then plain atomic scatter.

#define ROW_C 64
#define TBIT (1 << 30)
#define SCAN_T 256
#define SCAN_PER 16
#define SCAN_CHUNK (SCAN_T * SCAN_PER)

typedef float f32x4 __attribute__((ext_vector_type(4)));
typedef unsigned long long u64;

__device__ __forceinline__ f32x4 feat_load(const float* __restrict__ feat1,
                                           const float* __restrict__ feat2,
                                           int v, int sub) {
    const float* f = (v & TBIT) ? feat2 : feat1;
    int ir = v & (TBIT - 1);
    return *reinterpret_cast<const f32x4*>(f + (size_t)ir * ROW_C + sub);
}

// ---------- linked-list path ----------
__global__ __launch_bounds__(256) void k_fill_list(
        const int* __restrict__ m1i, const int* __restrict__ m1o,
        const int* __restrict__ m2i, const int* __restrict__ m2o,
        int n1, int n2,
        u64* __restrict__ head, u64* __restrict__ entries) {
    int i = blockIdx.x * blockDim.x + threadIdx.x;
    int r, v;
    if (i < n1) { r = m1o[i]; v = m1i[i]; }
    else {
        int j = i - n1;
        if (j >= n2) return;
        r = m2o[j]; v = m2i[j] | TBIT;
    }
    u64 packed = ((u64)(unsigned)i << 32) | (unsigned)v;
    u64 old = atomicExch(&head[r], packed);   // only random op: 12MB region
    entries[i] = old;                          // coalesced streaming store
}

__global__ __launch_bounds__(256) void k_gather_list(
        const float* __restrict__ feat1, const float* __restrict__ feat2,
        const u64* __restrict__ head, const u64* __restrict__ entries,
        float* __restrict__ out, int M) {
    int gid = blockIdx.x * blockDim.x + threadIdx.x;
    int row = gid >> 4;                 // 16 threads per output row
    if (row >= M) return;
    int sub = (gid & 15) << 2;

    u64 cur = head[row];                // lanes 0-15 broadcast same address
    f32x4 acc = {0.f, 0.f, 0.f, 0.f};

    // Collect up to 4 source ids into named registers (no dynamic indexing).
    int v0 = (int)(unsigned)cur, v1 = -1, v2 = -1, v3 = -1;
    if (v0 != -1) {
        int nx = (int)(cur >> 32);
        if (nx >= 0) {
            cur = entries[nx]; v1 = (int)(unsigned)cur;
            if (v1 != -1) {
                nx = (int)(cur >> 32);
                if (nx >= 0) {
                    cur = entries[nx]; v2 = (int)(unsigned)cur;
                    if (v2 != -1) {
                        nx = (int)(cur >> 32);
                        if (nx >= 0) {
                            cur = entries[nx]; v3 = (int)(unsigned)cur;
                            if (v3 != -1) {
                                nx = (int)(cur >> 32);
                                // rare fan-in > 4: accumulate inline
                                while (nx >= 0) {
                                    cur = entries[nx];
                                    int v = (int)(unsigned)cur;
                                    if (v == -1) break;
                                    acc += feat_load(feat1, feat2, v, sub);
                                    nx = (int)(cur >> 32);
                                }
                            }
                        }
                    }
                }
            }
        }
    }

    // Independent feature-row loads (MLP-friendly).
    if (v0 != -1) acc += feat_load(feat1, feat2, v0, sub);
    if (v1 != -1) acc += feat_load(feat1, feat2, v1, sub);
    if (v2 != -1) acc += feat_load(feat1, feat2, v2, sub);
    if (v3 != -1) acc += feat_load(feat1, feat2, v3, sub);

    __builtin_nontemporal_store(acc,
        reinterpret_cast<f32x4*>(out + (size_t)row * ROW_C + sub));
}

// ---------- CSR fallback ----------
__global__ void k_hist(const int* __restrict__ map_out, int n, int* __restrict__ counts) {
    int i = blockIdx.x * blockDim.x + threadIdx.x;
    if (i < n) atomicAdd(&counts[map_out[i]], 1);
}

__global__ void k_partial(const int* __restrict__ counts, int M, int* __restrict__ bsum) {
    __shared__ int lds[SCAN_T];
    int base = blockIdx.x * SCAN_CHUNK + threadIdx.x * SCAN_PER;
    int s = 0;
#pragma unroll
    for (int k = 0; k < SCAN_PER; k++) { int i = base + k; if (i < M) s += counts[i]; }
    lds[threadIdx.x] = s; __syncthreads();
    for (int off = SCAN_T / 2; off > 0; off >>= 1) {
        if (threadIdx.x < off) lds[threadIdx.x] += lds[threadIdx.x + off];
        __syncthreads();
    }
    if (threadIdx.x == 0) bsum[blockIdx.x] = lds[0];
}

__global__ void k_scan_bsum(int* __restrict__ bsum, int nblk) {
    __shared__ int lds[512];
    int t = threadIdx.x;
    lds[t] = (t < nblk) ? bsum[t] : 0;
    __syncthreads();
    for (int off = 1; off < 512; off <<= 1) {
        int v = (t >= off) ? lds[t - off] : 0;
        __syncthreads();
        lds[t] += v;
        __syncthreads();
    }
    if (t < nblk) bsum[t] = (t == 0) ? 0 : lds[t - 1];
}

__global__ void k_offsets(const int* __restrict__ counts, int M,
                          const int* __restrict__ bsum, int* __restrict__ cursor) {
    __shared__ int lds[SCAN_T];
    int base = blockIdx.x * SCAN_CHUNK + threadIdx.x * SCAN_PER;
    int c[SCAN_PER]; int s = 0;
#pragma unroll
    for (int k = 0; k < SCAN_PER; k++) { int i = base + k; c[k] = (i < M) ? counts[i] : 0; s += c[k]; }
    lds[threadIdx.x] = s; __syncthreads();
    for (int off = 1; off < SCAN_T; off <<= 1) {
        int v = (threadIdx.x >= off) ? lds[threadIdx.x - off] : 0;
        __syncthreads();
        lds[threadIdx.x] += v;
        __syncthreads();
    }
    int prefix = bsum[blockIdx.x] + ((threadIdx.x == 0) ? 0 : lds[threadIdx.x - 1]);
#pragma unroll
    for (int k = 0; k < SCAN_PER; k++) { int i = base + k; if (i < M) cursor[i] = prefix; prefix += c[k]; }
}

__global__ void k_fill(const int* __restrict__ map_in, const int* __restrict__ map_out,
                       int n, int tbit, int* __restrict__ cursor, int* __restrict__ csr) {
    int i = blockIdx.x * blockDim.x + threadIdx.x;
    if (i >= n) return;
    int r = map_out[i];
    int pos = atomicAdd(&cursor[r], 1);
    csr[pos] = map_in[i] | tbit;
}

__global__ void k_gather(const float* __restrict__ feat1, const float* __restrict__ feat2,
                         const int* __restrict__ counts, const int* __restrict__ cursor,
                         const int* __restrict__ csr, float* __restrict__ out, int M) {
    int gid = blockIdx.x * blockDim.x + threadIdx.x;
    int row = gid >> 4;
    if (row >= M) return;
    int sub = (gid & 15) << 2;

    int cnt = counts[row];
    int end = cursor[row];
    int start = end - cnt;

    float4 acc = {0.f, 0.f, 0.f, 0.f};
    for (int k = 0; k < cnt; k++) {
        int e = csr[start + k];
        const float* f = (e & TBIT) ? feat2 : feat1;
        int in_r = e & (TBIT - 1);
        float4 v = *reinterpret_cast<const float4*>(f + (size_t)in_r * ROW_C + sub);
        acc.x += v.x; acc.y += v.y; acc.z += v.z; acc.w += v.w;
    }
    *reinterpret_cast<float4*>(out + (size_t)row * ROW_C + sub) = acc;
}

// ---------- last-resort atomic scatter ----------
__global__ void scatter_add_rows(const float* __restrict__ feat,
                                 const int* __restrict__ map_in,
                                 const int* __restrict__ map_out,
                                 float* __restrict__ out,
                                 int n_rows) {
    int gid = blockIdx.x * blockDim.x + threadIdx.x;
    int row = gid >> 4;
    if (row >= n_rows) return;
    int sub = (gid & 15) << 2;
    int in_r  = map_in[row];
    int out_r = map_out[row];
    const float4 v = *reinterpret_cast<const float4*>(feat + (size_t)in_r * ROW_C + sub);
    float* o = out + (size_t)out_r * ROW_C + sub;
    unsafeAtomicAdd(o + 0, v.x);
    unsafeAtomicAdd(o + 1, v.y);
    unsafeAtomicAdd(o + 2, v.z);
    unsafeAtomicAdd(o + 3, v.w);
}

extern "C" void kernel_launch(void* const* d_in, const int* in_sizes, int n_in,
                              void* d_out, int out_size, void* d_ws, size_t ws_size,
                              hipStream_t stream) {
    const float* feat1    = (const float*)d_in[0];
    const float* feat2    = (const float*)d_in[1];
    const int*   map1_in  = (const int*)d_in[2];
    const int*   map1_out = (const int*)d_in[3];
    const int*   map2_in  = (const int*)d_in[4];
    const int*   map2_out = (const int*)d_in[5];
    float* out = (float*)d_out;

    const int n1 = in_sizes[2];
    const int n2 = in_sizes[4];
    const int M  = out_size / ROW_C;
    const int ntot = n1 + n2;
    const int block = 256;

    // ---- linked-list path ----
    // layout: head[M] (u64) | entries[ntot] (u64)
    const size_t need_list = ((size_t)M + (size_t)ntot) * sizeof(u64);
    if (ws_size >= need_list) {
        u64* head    = (u64*)d_ws;
        u64* entries = head + M;

        hipMemsetAsync(head, 0xFF, (size_t)M * sizeof(u64), stream);  // {-1,-1}

        int gridf = (ntot + block - 1) / block;
        k_fill_list<<<gridf, block, 0, stream>>>(map1_in, map1_out, map2_in, map2_out,
                                                 n1, n2, head, entries);

        int gridg = (int)(((long long)M * 16 + block - 1) / block);
        k_gather_list<<<gridg, block, 0, stream>>>(feat1, feat2, head, entries, out, M);
        return;
    }

    // ---- CSR fallback ----
    const int nblk = (M + SCAN_CHUNK - 1) / SCAN_CHUNK;
    const size_t need_csr = (size_t)(2 * (size_t)M + (size_t)ntot + (size_t)nblk) * sizeof(int);
    if (ws_size >= need_csr && nblk <= 512) {
        int* counts = (int*)d_ws;
        int* cursor = counts + M;
        int* csr    = cursor + M;
        int* bsum   = csr + ntot;

        hipMemsetAsync(counts, 0, (size_t)M * sizeof(int), stream);
        k_hist<<<(n1 + block - 1) / block, block, 0, stream>>>(map1_out, n1, counts);
        k_hist<<<(n2 + block - 1) / block, block, 0, stream>>>(map2_out, n2, counts);
        k_partial<<<nblk, SCAN_T, 0, stream>>>(counts, M, bsum);
        k_scan_bsum<<<1, 512, 0, stream>>>(bsum, nblk);
        k_offsets<<<nblk, SCAN_T, 0, stream>>>(counts, M, bsum, cursor);
        k_fill<<<(n1 + block - 1) / block, block, 0, stream>>>(map1_in, map1_out, n1, 0, cursor, csr);
        k_fill<<<(n2 + block - 1) / block, block, 0, stream>>>(map2_in, map2_out, n2, TBIT, cursor, csr);
        int gridg = (int)(((long long)M * 16 + block - 1) / block);
        k_gather<<<gridg, block, 0, stream>>>(feat1, feat2, counts, cursor, csr, out, M);
        return;
    }

    // ---- atomic scatter ----
    hipMemsetAsync(out, 0, (size_t)out_size * sizeof(float), stream);
    int grid1 = (int)(((long long)n1 * 16 + block - 1) / block);
    int grid2 = (int)(((long long)n2 * 16 + block - 1) / block);
    scatter_add_rows<<<grid1, block, 0, stream>>>(feat1, map1_in, map1_out, out, n1);
    scatter_add_rows<<<grid2, block, 0, stream>>>(feat2, map2_in, map2_out, out, n2);
}

// Round 7
// 327.904 us; speedup vs baseline: 1.5889x; 1.1523x over previous
//
#include <hip/hip_runtime.h>

// MinkowskiUnion: out[map_out[i]] += feat[map_in[i]] for two input tensors.
// Three-phase inversion:
//   1) k_fill_list: old = atomicExch(&head[r], {i, v}); entries[i] = old.
//      Random traffic ONLY on the 12 MB head (IF-resident); entries stores
//      coalesced. (Proven ~55 us in round 6.)
//   2) k_compact: one thread per output row walks its chain (entries is a
//      16 MB IF-resident array) and writes rec[r] = {s0,s1,s2,s3} coalesced.
//      Fan-in > 4 (~0.9% of rows): s3 = 0x80000000 | entry_idx continuation.
//   3) k_gather_rec4: 16 lanes/row read rec (16 B), issue up to 4 INDEPENDENT
//      feat row loads, one NT store per row. (Proven ~227 us in round 5.)
// No f32 atomics anywhere. Fallbacks: CSR counting-sort, then atomic scatter.

#define ROW_C 64
#define TBIT (1 << 30)
#define CONT 0x80000000u
#define SCAN_T 256
#define SCAN_PER 16
#define SCAN_CHUNK (SCAN_T * SCAN_PER)

typedef float f32x4 __attribute__((ext_vector_type(4)));
typedef unsigned long long u64;

__device__ __forceinline__ f32x4 feat_load(const float* __restrict__ feat1,
                                           const float* __restrict__ feat2,
                                           int v, int sub) {
    const float* f = (v & TBIT) ? feat2 : feat1;
    int ir = v & (TBIT - 1);
    return *reinterpret_cast<const f32x4*>(f + (size_t)ir * ROW_C + sub);
}

// ---------- phase 1: linked-list fill ----------
__global__ __launch_bounds__(256) void k_fill_list(
        const int* __restrict__ m1i, const int* __restrict__ m1o,
        const int* __restrict__ m2i, const int* __restrict__ m2o,
        int n1, int n2,
        u64* __restrict__ head, u64* __restrict__ entries) {
    int i = blockIdx.x * blockDim.x + threadIdx.x;
    int r, v;
    if (i < n1) { r = m1o[i]; v = m1i[i]; }
    else {
        int j = i - n1;
        if (j >= n2) return;
        r = m2o[j]; v = m2i[j] | TBIT;
    }
    u64 packed = ((u64)(unsigned)i << 32) | (unsigned)v;
    u64 old = atomicExch(&head[r], packed);   // only random op: 12 MB region
    entries[i] = old;                          // coalesced streaming store
}

// ---------- phase 2: chains -> 16B slot records ----------
__global__ __launch_bounds__(256) void k_compact(
        const u64* __restrict__ head, const u64* __restrict__ entries,
        int* __restrict__ rec, int M) {
    int r = blockIdx.x * blockDim.x + threadIdx.x;
    if (r >= M) return;
    u64 cur = head[r];                 // coalesced
    int s0 = -1, s1 = -1, s2 = -1, s3 = -1;
    int v = (int)(unsigned)cur;
    if (v != -1) {
        s0 = v;
        cur = entries[(int)(cur >> 32)];
        v = (int)(unsigned)cur;
        if (v != -1) {
            s1 = v;
            cur = entries[(int)(cur >> 32)];
            v = (int)(unsigned)cur;
            if (v != -1) {
                s2 = v;
                int nx = (int)(cur >> 32);    // index holding pair 4
                cur = entries[nx];
                v = (int)(unsigned)cur;
                if (v != -1) {
                    u64 peek = entries[(int)(cur >> 32)];
                    if ((int)(unsigned)peek == -1) {
                        s3 = v;                              // exactly 4
                    } else {
                        s3 = (int)(CONT | (unsigned)nx);     // >4: resume at pair 4
                    }
                }
            }
        }
    }
    int4 q = { s0, s1, s2, s3 };
    *reinterpret_cast<int4*>(rec + ((size_t)r << 2)) = q;    // coalesced
}

// ---------- phase 3: direct gather ----------
__global__ __launch_bounds__(256) void k_gather_rec4(
        const float* __restrict__ feat1, const float* __restrict__ feat2,
        const int* __restrict__ rec, const u64* __restrict__ entries,
        float* __restrict__ out, int M) {
    int gid = blockIdx.x * blockDim.x + threadIdx.x;
    int row = gid >> 4;                 // 16 threads per output row
    if (row >= M) return;
    int sub = (gid & 15) << 2;

    const int4 s = *reinterpret_cast<const int4*>(rec + ((size_t)row << 2));

    f32x4 acc = {0.f, 0.f, 0.f, 0.f};
    if (s.x != -1) acc += feat_load(feat1, feat2, s.x, sub);
    if (s.y != -1) acc += feat_load(feat1, feat2, s.y, sub);
    if (s.z != -1) acc += feat_load(feat1, feat2, s.z, sub);
    if (s.w != -1) {
        if ((unsigned)s.w & CONT) {
            u64 cur = entries[s.w & 0x7FFFFFFF];   // rare (~0.9% of rows)
            int v = (int)(unsigned)cur;
            while (v != -1) {
                acc += feat_load(feat1, feat2, v, sub);
                cur = entries[(int)(cur >> 32)];
                v = (int)(unsigned)cur;
            }
        } else {
            acc += feat_load(feat1, feat2, s.w, sub);
        }
    }

    __builtin_nontemporal_store(acc,
        reinterpret_cast<f32x4*>(out + (size_t)row * ROW_C + sub));
}

// ---------- CSR fallback ----------
__global__ void k_hist(const int* __restrict__ map_out, int n, int* __restrict__ counts) {
    int i = blockIdx.x * blockDim.x + threadIdx.x;
    if (i < n) atomicAdd(&counts[map_out[i]], 1);
}

__global__ void k_partial(const int* __restrict__ counts, int M, int* __restrict__ bsum) {
    __shared__ int lds[SCAN_T];
    int base = blockIdx.x * SCAN_CHUNK + threadIdx.x * SCAN_PER;
    int s = 0;
#pragma unroll
    for (int k = 0; k < SCAN_PER; k++) { int i = base + k; if (i < M) s += counts[i]; }
    lds[threadIdx.x] = s; __syncthreads();
    for (int off = SCAN_T / 2; off > 0; off >>= 1) {
        if (threadIdx.x < off) lds[threadIdx.x] += lds[threadIdx.x + off];
        __syncthreads();
    }
    if (threadIdx.x == 0) bsum[blockIdx.x] = lds[0];
}

__global__ void k_scan_bsum(int* __restrict__ bsum, int nblk) {
    __shared__ int lds[512];
    int t = threadIdx.x;
    lds[t] = (t < nblk) ? bsum[t] : 0;
    __syncthreads();
    for (int off = 1; off < 512; off <<= 1) {
        int v = (t >= off) ? lds[t - off] : 0;
        __syncthreads();
        lds[t] += v;
        __syncthreads();
    }
    if (t < nblk) bsum[t] = (t == 0) ? 0 : lds[t - 1];
}

__global__ void k_offsets(const int* __restrict__ counts, int M,
                          const int* __restrict__ bsum, int* __restrict__ cursor) {
    __shared__ int lds[SCAN_T];
    int base = blockIdx.x * SCAN_CHUNK + threadIdx.x * SCAN_PER;
    int c[SCAN_PER]; int s = 0;
#pragma unroll
    for (int k = 0; k < SCAN_PER; k++) { int i = base + k; c[k] = (i < M) ? counts[i] : 0; s += c[k]; }
    lds[threadIdx.x] = s; __syncthreads();
    for (int off = 1; off < SCAN_T; off <<= 1) {
        int v = (threadIdx.x >= off) ? lds[threadIdx.x - off] : 0;
        __syncthreads();
        lds[threadIdx.x] += v;
        __syncthreads();
    }
    int prefix = bsum[blockIdx.x] + ((threadIdx.x == 0) ? 0 : lds[threadIdx.x - 1]);
#pragma unroll
    for (int k = 0; k < SCAN_PER; k++) { int i = base + k; if (i < M) cursor[i] = prefix; prefix += c[k]; }
}

__global__ void k_fill(const int* __restrict__ map_in, const int* __restrict__ map_out,
                       int n, int tbit, int* __restrict__ cursor, int* __restrict__ csr) {
    int i = blockIdx.x * blockDim.x + threadIdx.x;
    if (i >= n) return;
    int r = map_out[i];
    int pos = atomicAdd(&cursor[r], 1);
    csr[pos] = map_in[i] | tbit;
}

__global__ void k_gather(const float* __restrict__ feat1, const float* __restrict__ feat2,
                         const int* __restrict__ counts, const int* __restrict__ cursor,
                         const int* __restrict__ csr, float* __restrict__ out, int M) {
    int gid = blockIdx.x * blockDim.x + threadIdx.x;
    int row = gid >> 4;
    if (row >= M) return;
    int sub = (gid & 15) << 2;

    int cnt = counts[row];
    int end = cursor[row];
    int start = end - cnt;

    float4 acc = {0.f, 0.f, 0.f, 0.f};
    for (int k = 0; k < cnt; k++) {
        int e = csr[start + k];
        const float* f = (e & TBIT) ? feat2 : feat1;
        int in_r = e & (TBIT - 1);
        float4 v = *reinterpret_cast<const float4*>(f + (size_t)in_r * ROW_C + sub);
        acc.x += v.x; acc.y += v.y; acc.z += v.z; acc.w += v.w;
    }
    *reinterpret_cast<float4*>(out + (size_t)row * ROW_C + sub) = acc;
}

// ---------- last-resort atomic scatter ----------
__global__ void scatter_add_rows(const float* __restrict__ feat,
                                 const int* __restrict__ map_in,
                                 const int* __restrict__ map_out,
                                 float* __restrict__ out,
                                 int n_rows) {
    int gid = blockIdx.x * blockDim.x + threadIdx.x;
    int row = gid >> 4;
    if (row >= n_rows) return;
    int sub = (gid & 15) << 2;
    int in_r  = map_in[row];
    int out_r = map_out[row];
    const float4 v = *reinterpret_cast<const float4*>(feat + (size_t)in_r * ROW_C + sub);
    float* o = out + (size_t)out_r * ROW_C + sub;
    unsafeAtomicAdd(o + 0, v.x);
    unsafeAtomicAdd(o + 1, v.y);
    unsafeAtomicAdd(o + 2, v.z);
    unsafeAtomicAdd(o + 3, v.w);
}

extern "C" void kernel_launch(void* const* d_in, const int* in_sizes, int n_in,
                              void* d_out, int out_size, void* d_ws, size_t ws_size,
                              hipStream_t stream) {
    const float* feat1    = (const float*)d_in[0];
    const float* feat2    = (const float*)d_in[1];
    const int*   map1_in  = (const int*)d_in[2];
    const int*   map1_out = (const int*)d_in[3];
    const int*   map2_in  = (const int*)d_in[4];
    const int*   map2_out = (const int*)d_in[5];
    float* out = (float*)d_out;

    const int n1 = in_sizes[2];
    const int n2 = in_sizes[4];
    const int M  = out_size / ROW_C;
    const int ntot = n1 + n2;
    const int block = 256;

    // ---- list + compact + rec path ----
    // layout: head[M] u64 | entries[ntot] u64 | rec[4M] int
    const size_t need_list = ((size_t)M + (size_t)ntot) * sizeof(u64)
                           + ((size_t)M * 4) * sizeof(int);
    if (ws_size >= need_list) {
        u64* head    = (u64*)d_ws;
        u64* entries = head + M;
        int* rec     = (int*)(entries + ntot);

        hipMemsetAsync(head, 0xFF, (size_t)M * sizeof(u64), stream);  // {-1,-1}

        int gridf = (ntot + block - 1) / block;
        k_fill_list<<<gridf, block, 0, stream>>>(map1_in, map1_out, map2_in, map2_out,
                                                 n1, n2, head, entries);

        int gridc = (M + block - 1) / block;
        k_compact<<<gridc, block, 0, stream>>>(head, entries, rec, M);

        int gridg = (int)(((long long)M * 16 + block - 1) / block);
        k_gather_rec4<<<gridg, block, 0, stream>>>(feat1, feat2, rec, entries, out, M);
        return;
    }

    // ---- CSR fallback ----
    const int nblk = (M + SCAN_CHUNK - 1) / SCAN_CHUNK;
    const size_t need_csr = (size_t)(2 * (size_t)M + (size_t)ntot + (size_t)nblk) * sizeof(int);
    if (ws_size >= need_csr && nblk <= 512) {
        int* counts = (int*)d_ws;
        int* cursor = counts + M;
        int* csr    = cursor + M;
        int* bsum   = csr + ntot;

        hipMemsetAsync(counts, 0, (size_t)M * sizeof(int), stream);
        k_hist<<<(n1 + block - 1) / block, block, 0, stream>>>(map1_out, n1, counts);
        k_hist<<<(n2 + block - 1) / block, block, 0, stream>>>(map2_out, n2, counts);
        k_partial<<<nblk, SCAN_T, 0, stream>>>(counts, M, bsum);
        k_scan_bsum<<<1, 512, 0, stream>>>(bsum, nblk);
        k_offsets<<<nblk, SCAN_T, 0, stream>>>(counts, M, bsum, cursor);
        k_fill<<<(n1 + block - 1) / block, block, 0, stream>>>(map1_in, map1_out, n1, 0, cursor, csr);
        k_fill<<<(n2 + block - 1) / block, block, 0, stream>>>(map2_in, map2_out, n2, TBIT, cursor, csr);
        int gridg = (int)(((long long)M * 16 + block - 1) / block);
        k_gather<<<gridg, block, 0, stream>>>(feat1, feat2, counts, cursor, csr, out, M);
        return;
    }

    // ---- atomic scatter ----
    hipMemsetAsync(out, 0, (size_t)out_size * sizeof(float), stream);
    int grid1 = (int)(((long long)n1 * 16 + block - 1) / block);
    int grid2 = (int)(((long long)n2 * 16 + block - 1) / block);
    scatter_add_rows<<<grid1, block, 0, stream>>>(feat1, map1_in, map1_out, out, n1);
    scatter_add_rows<<<grid2, block, 0, stream>>>(feat2, map2_in, map2_out, out, n2);
}